// Round 10
// baseline (354.676 us; speedup 1.0000x reference)
//
#include <hip/hip_runtime.h>
#include <math.h>

#define BN 4096
#define N_PER_B 64
#define NE 16384
#define NSEL 65536
#define NET 5
#define PD 64
#define H1STR 260   // pair LDS stride (shorts)
#define FSTR 264    // fstep LDS stride (shorts)
#define PTILES 4

typedef float f32x4 __attribute__((ext_vector_type(4)));
typedef float f32x16 __attribute__((ext_vector_type(16)));
typedef short short8 __attribute__((ext_vector_type(8)));
typedef short short4v __attribute__((ext_vector_type(4)));

__device__ __forceinline__ unsigned short f2bf(float f) {
    unsigned int u = __builtin_bit_cast(unsigned int, f);
    u += 0x7fff + ((u >> 16) & 1);          // RNE
    return (unsigned short)(u >> 16);
}
__device__ __forceinline__ float bf_lo(unsigned int u) {
    return __builtin_bit_cast(float, u << 16);
}
__device__ __forceinline__ float bf_hi(unsigned int u) {
    return __builtin_bit_cast(float, u & 0xffff0000u);
}
__device__ __forceinline__ unsigned int pack2(float a, float b) {
    return (unsigned)f2bf(a) | ((unsigned)f2bf(b) << 16);
}
__device__ __forceinline__ short8 ld_frag(const unsigned short* p) {
    const short4v lo = *(const short4v*)(p);
    const short4v hi = *(const short4v*)(p + 4);
    return __builtin_shufflevector(lo, hi, 0, 1, 2, 3, 4, 5, 6, 7);
}
__device__ __forceinline__ unsigned int addrelu2(unsigned int a, unsigned int b, unsigned int c) {
    const float lo = fmaxf(bf_lo(a) + bf_lo(b) + bf_lo(c), 0.f);
    const float hi = fmaxf(bf_hi(a) + bf_hi(b) + bf_hi(c), 0.f);
    return pack2(lo, hi);
}

// ---------------------------------------------------------------------------
// Single-block CSR build: LDS hist -> scan -> scatter.
// recs[pos] = (src, dst); epos[e] = CSR slot of edge e (for ET placement).
// ---------------------------------------------------------------------------
__global__ __launch_bounds__(1024) void csr_all(const int* __restrict__ eidx,
                                                int* __restrict__ row_start,
                                                int2* __restrict__ recs,
                                                int* __restrict__ epos)
{
    __shared__ int sdeg[4096];
    __shared__ int scan1[1024];
    const int tid = threadIdx.x;
    #pragma unroll
    for (int i = 0; i < 4; ++i) sdeg[tid * 4 + i] = 0;
    __syncthreads();
    #pragma unroll
    for (int r = 0; r < NE / 1024; ++r)
        atomicAdd(&sdeg[eidx[NE + r * 1024 + tid]], 1);
    __syncthreads();
    const int l0 = sdeg[tid * 4 + 0];
    const int l1 = sdeg[tid * 4 + 1];
    const int l2 = sdeg[tid * 4 + 2];
    const int l3 = sdeg[tid * 4 + 3];
    scan1[tid] = l0 + l1 + l2 + l3;
    __syncthreads();
    for (int off = 1; off < 1024; off <<= 1) {
        const int v = scan1[tid];
        const int add = (tid >= off) ? scan1[tid - off] : 0;
        __syncthreads();
        scan1[tid] = v + add;
        __syncthreads();
    }
    const int base = (tid == 0) ? 0 : scan1[tid - 1];
    row_start[tid * 4 + 0] = base;
    row_start[tid * 4 + 1] = base + l0;
    row_start[tid * 4 + 2] = base + l0 + l1;
    row_start[tid * 4 + 3] = base + l0 + l1 + l2;
    sdeg[tid * 4 + 0] = base;
    sdeg[tid * 4 + 1] = base + l0;
    sdeg[tid * 4 + 2] = base + l0 + l1;
    sdeg[tid * 4 + 3] = base + l0 + l1 + l2;
    if (tid == 0) row_start[4096] = NE;
    __syncthreads();
    #pragma unroll
    for (int r = 0; r < NE / 1024; ++r) {
        const int e = r * 1024 + tid;
        const int d = eidx[NE + e];
        const int s = eidx[e];
        const int pos = atomicAdd(&sdeg[d], 1);
        int2 rec; rec.x = s; rec.y = d;
        recs[pos] = rec;
        epos[e] = pos;
    }
}

// ---------------------------------------------------------------------------
// Preamble mega-kernel:
//  [0,128)    weight convert/transpose fp32 [K][256] -> bf16 [256][K]
//  [128,192)  prop_add  (blk 128 also zeroes d_out)
//  [192,449)  Wfold = W3@W_out -> bf16 WfT[16][256] + bfv
//  [449,577)  ETc[pos][c] = eattr_e @ Wm_e + b_msg  (CSR-ordered via epos)
// ---------------------------------------------------------------------------
__global__ __launch_bounds__(256) void k_pre(
    const float* __restrict__ W_in, const float* __restrict__ W_msg,
    const float* __restrict__ W_upd, const float* __restrict__ W_add,
    const float* __restrict__ W1, const float* __restrict__ W2,
    const float* __restrict__ W3, const float* __restrict__ b3,
    const float* __restrict__ W_out, const float* __restrict__ b_out,
    const float* __restrict__ props, const float* __restrict__ W_prop,
    const float* __restrict__ b_prop, const float* __restrict__ b_add,
    const float* __restrict__ b_msg, const float* __restrict__ eattr,
    const int* __restrict__ epos,
    unsigned short* __restrict__ wbf, unsigned short* __restrict__ WfT,
    float* __restrict__ bfv, float* __restrict__ prop_add,
    unsigned short* __restrict__ ETc, float* __restrict__ dout)
{
    __shared__ __align__(16) char smem[16704];
    const int blk = blockIdx.x;
    const int tid = threadIdx.x;

    if (blk < 128) {                          // ---- weight convert/transpose
        float (*s)[65] = (float(*)[65])smem;
        const int wsel = blk >> 4;
        const int sub = blk & 15;
        const float* src; unsigned short* dst; int K = 256;
        switch (wsel) {
            case 0: src = W_in;              dst = wbf;                         K = 192; break;
            case 1: src = W_msg;             dst = wbf + 49152;                 break;
            case 2: src = W_upd;             dst = wbf + 49152 + 65536;         break;
            case 3: src = W_upd + 256 * 256; dst = wbf + 49152 + 2 * 65536;     break;
            case 4: src = W_add;             dst = wbf + 49152 + 3 * 65536;     break;
            case 5: src = W1;                dst = wbf + 49152 + 4 * 65536;     break;
            case 6: src = W1 + 256 * 256;    dst = wbf + 49152 + 5 * 65536;     break;
            default: src = W2;               dst = wbf + 49152 + 6 * 65536;     break;
        }
        const int k0 = (sub >> 2) * 64;
        const int n0 = (sub & 3) * 64;
        if (k0 >= K) return;
        const int tn = tid & 63;
        const int tg = tid >> 6;
        #pragma unroll
        for (int i = 0; i < 16; ++i) {
            const int kk = tg * 16 + i;
            s[kk][tn] = src[(size_t)(k0 + kk) * 256 + n0 + tn];
        }
        __syncthreads();
        #pragma unroll
        for (int i = 0; i < 16; ++i) {
            const int nn = tg * 16 + i;
            dst[(size_t)(n0 + nn) * K + k0 + tn] = f2bf(s[tn][nn]);
        }
    } else if (blk < 192) {                   // ---- prop_add (+ d_out zero)
        const int b = blk - 128;
        if (b == 0 && tid == 0) *dout = 0.f;
        const float pv = props[b];
        float acc = b_add[tid];
        #pragma unroll 8
        for (int p = 0; p < PD; ++p) {
            const float e = fmaf(pv, W_prop[p], b_prop[p]);
            acc = fmaf(e, W_add[(256 + p) * 256 + tid], acc);
        }
        prop_add[b * 256 + tid] = acc;
    } else if (blk < 449) {                   // ---- Wfold + bfv
        float* part = (float*)smem;           // [4][NET]
        const int cb = blk - 192;             // 0..256
        float acc[NET] = {0.f, 0.f, 0.f, 0.f, 0.f};
        #pragma unroll
        for (int rep = 0; rep < 2; ++rep) {
            const int j = rep * 256 + tid;
            const float wv = (cb < 256) ? W3[(size_t)cb * 512 + j] : b3[j];
            #pragma unroll
            for (int t = 0; t < NET; ++t) acc[t] = fmaf(wv, W_out[j * NET + t], acc[t]);
        }
        #pragma unroll
        for (int t = 0; t < NET; ++t)
            for (int off = 32; off >= 1; off >>= 1) acc[t] += __shfl_down(acc[t], off);
        if ((tid & 63) == 0) {
            #pragma unroll
            for (int t = 0; t < NET; ++t) part[(tid >> 6) * NET + t] = acc[t];
        }
        __syncthreads();
        if (tid == 0) {
            float s[NET];
            #pragma unroll
            for (int t = 0; t < NET; ++t)
                s[t] = part[t] + part[NET + t] + part[2 * NET + t] + part[3 * NET + t];
            if (cb < 256) {
                #pragma unroll
                for (int t = 0; t < NET; ++t) WfT[t * 256 + cb] = f2bf(s[t]);
                #pragma unroll
                for (int t = NET; t < 16; ++t) WfT[t * 256 + cb] = 0;
            } else {
                #pragma unroll
                for (int t = 0; t < NET; ++t) bfv[t] = s[t] + b_out[t];
            }
        }
    } else {                                  // ---- edge term ETc (CSR-ordered)
        float* ea = (float*)smem;             // [128*5]
        int* eposs = (int*)(smem + 2560 + 64);
        const int eb = (blk - 449) * 128;
        if (tid < 160)
            *(float4*)&ea[tid * 4] = *(const float4*)(eattr + (size_t)eb * 5 + tid * 4);
        if (tid < 128) eposs[tid] = epos[eb + tid];
        __syncthreads();
        const float* Wme = W_msg + 256 * 256;
        const float w0 = Wme[0 * 256 + tid];
        const float w1 = Wme[1 * 256 + tid];
        const float w2 = Wme[2 * 256 + tid];
        const float w3 = Wme[3 * 256 + tid];
        const float w4 = Wme[4 * 256 + tid];
        const float bm = b_msg[tid];
        for (int i = 0; i < 128; ++i) {
            const float* a = ea + i * 5;
            float v = bm;
            v = fmaf(a[0], w0, v); v = fmaf(a[1], w1, v); v = fmaf(a[2], w2, v);
            v = fmaf(a[3], w3, v); v = fmaf(a[4], w4, v);
            ETc[(size_t)eposs[i] * 256 + tid] = f2bf(v);
        }
    }
}

// ---------------------------------------------------------------------------
// Fused node step. 1024 threads = 16 waves; 16 node-rows/block (grid 256).
// Phase A (modes 1,2): balanced cooperative agg — all 16 waves stride over the
// block's contiguous CSR span, accumulating into an fp32 LDS tile via LDS
// atomics (kills the worst-node tail the old wave<->node mapping had).
// Phase B: act = relu(h@Wua + agg@Wub + b)   (mode 0: relu(x@W_in+b))
// Phase C: P = act@Wm (modes 0,1) | embg=act@W_add+prop -> A1,A2 (mode 2)
// ---------------------------------------------------------------------------
__global__ __launch_bounds__(1024) void fstep(
    const float* __restrict__ x, const unsigned short* __restrict__ hbuf,
    const unsigned short* __restrict__ Pin, const unsigned short* __restrict__ ETc,
    const int* __restrict__ row_start, const int2* __restrict__ recs,
    const unsigned short* __restrict__ WaT, const unsigned short* __restrict__ WbT,
    const float* __restrict__ bias1,
    const unsigned short* __restrict__ Wp2T, const float* __restrict__ prop_add,
    const unsigned short* __restrict__ W1aT, const unsigned short* __restrict__ W1bT,
    unsigned short* __restrict__ hout, unsigned short* __restrict__ out1,
    unsigned short* __restrict__ out2, int mode)
{
    __shared__ __align__(16) unsigned short Hg[16 * FSTR];   // staged h tile
    __shared__ __align__(16) float Agf[16 * 256];            // fp32 agg accum
    __shared__ __align__(16) unsigned short Ag[16 * FSTR];   // agg tile (bf16)
    __shared__ __align__(16) unsigned short Hs[16 * FSTR];   // act
    __shared__ __align__(16) unsigned short H2s[16 * FSTR];  // embg (mode 2)
    const int tid = threadIdx.x;
    const int w = tid >> 6;          // 0..15
    const int lane = tid & 63;
    const int q = lane >> 4;
    const int tx = lane & 15;
    const int m0 = blockIdx.x * 16;
    const int col = w * 16 + tx;

    // ---- phase A: stage h tile + cooperative agg (modes 1,2)
    if (mode != 0) {
        #pragma unroll
        for (int i = 0; i < 4; ++i) Agf[tid * 4 + i] = 0.f;
        {
            const int r = tid >> 6;
            const int c4 = (tid & 63) * 4;
            *(uint2*)&Hg[r * FSTR + c4] =
                *(const uint2*)(hbuf + (size_t)(m0 + r) * 256 + c4);
        }
        __syncthreads();
        {
            const int beg = row_start[m0];
            const int end = row_start[m0 + 16];
            const int c = lane * 4;
            for (int slot = beg + w; slot < end; slot += 16) {
                const int2 rec = recs[slot];          // (src, dst)
                const uint2 pu = *(const uint2*)(Pin + (size_t)rec.x * 256 + c);
                const uint2 eu = *(const uint2*)(ETc + (size_t)slot * 256 + c);
                float* arow = Agf + (rec.y - m0) * 256 + c;
                atomicAdd(arow + 0, fmaxf(bf_lo(pu.x) + bf_lo(eu.x), 0.f));
                atomicAdd(arow + 1, fmaxf(bf_hi(pu.x) + bf_hi(eu.x), 0.f));
                atomicAdd(arow + 2, fmaxf(bf_lo(pu.y) + bf_lo(eu.y), 0.f));
                atomicAdd(arow + 3, fmaxf(bf_hi(pu.y) + bf_hi(eu.y), 0.f));
            }
        }
        __syncthreads();
        {
            const int r = tid >> 6;
            const int c4 = (tid & 63) * 4;
            const float* s = Agf + r * 256 + c4;
            uint2 o; o.x = pack2(s[0], s[1]); o.y = pack2(s[2], s[3]);
            *(uint2*)&Ag[r * FSTR + c4] = o;
        }
        __syncthreads();
    }

    // ---- phase B: act = relu(A@W + b), wave w -> one 16-col tile
    f32x4 acc = (f32x4)0.f;
    if (mode == 0) {
        #pragma unroll
        for (int s = 0; s < 6; ++s) {
            const int k0 = s * 32;
            const float* ap = x + (size_t)(m0 + tx) * 192 + k0 + q * 8;
            const float4 v0 = *(const float4*)ap;
            const float4 v1 = *(const float4*)(ap + 4);
            short8 af;
            af[0] = (short)f2bf(v0.x); af[1] = (short)f2bf(v0.y);
            af[2] = (short)f2bf(v0.z); af[3] = (short)f2bf(v0.w);
            af[4] = (short)f2bf(v1.x); af[5] = (short)f2bf(v1.y);
            af[6] = (short)f2bf(v1.z); af[7] = (short)f2bf(v1.w);
            const short8 bfr = *(const short8*)(WaT + (size_t)col * 192 + k0 + q * 8);
            acc = __builtin_amdgcn_mfma_f32_16x16x32_bf16(af, bfr, acc, 0, 0, 0);
        }
    } else {
        #pragma unroll
        for (int s = 0; s < 8; ++s) {
            const int k0 = s * 32;
            const short8 af = *(const short8*)&Hg[tx * FSTR + k0 + q * 8];
            const short8 bfr = *(const short8*)(WaT + (size_t)col * 256 + k0 + q * 8);
            acc = __builtin_amdgcn_mfma_f32_16x16x32_bf16(af, bfr, acc, 0, 0, 0);
        }
        #pragma unroll
        for (int s = 0; s < 8; ++s) {
            const int k0 = s * 32;
            const short8 af = *(const short8*)&Ag[tx * FSTR + k0 + q * 8];
            const short8 bfr = *(const short8*)(WbT + (size_t)col * 256 + k0 + q * 8);
            acc = __builtin_amdgcn_mfma_f32_16x16x32_bf16(af, bfr, acc, 0, 0, 0);
        }
    }
    {
        const float bv = bias1[col];
        #pragma unroll
        for (int r = 0; r < 4; ++r) {
            const int row = q * 4 + r;
            const unsigned short us = f2bf(fmaxf(acc[r] + bv, 0.f));
            Hs[row * FSTR + col] = us;
            if (mode < 2) hout[(size_t)(m0 + row) * 256 + col] = us;
        }
    }
    __syncthreads();

    // ---- phase C: act @ Wp2
    acc = (f32x4)0.f;
    #pragma unroll
    for (int s = 0; s < 8; ++s) {
        const int k0 = s * 32;
        const short8 af = *(const short8*)&Hs[tx * FSTR + k0 + q * 8];
        const short8 bfr = *(const short8*)(Wp2T + (size_t)col * 256 + k0 + q * 8);
        acc = __builtin_amdgcn_mfma_f32_16x16x32_bf16(af, bfr, acc, 0, 0, 0);
    }
    if (mode < 2) {
        #pragma unroll
        for (int r = 0; r < 4; ++r)
            out1[(size_t)(m0 + q * 4 + r) * 256 + col] = f2bf(acc[r]);
        return;
    }
    {
        const float pv = prop_add[(m0 >> 6) * 256 + col];
        #pragma unroll
        for (int r = 0; r < 4; ++r)
            H2s[(q * 4 + r) * FSTR + col] = f2bf(acc[r] + pv);
    }
    __syncthreads();

    // ---- phase 2b: A1 = embg@W1a, A2 = embg@W1b
    for (int which = 0; which < 2; ++which) {
        const unsigned short* WT = which ? W1bT : W1aT;
        unsigned short* op = which ? out2 : out1;
        acc = (f32x4)0.f;
        #pragma unroll
        for (int s = 0; s < 8; ++s) {
            const int k0 = s * 32;
            const short8 af = *(const short8*)&H2s[tx * FSTR + k0 + q * 8];
            const short8 bfr = *(const short8*)(WT + (size_t)col * 256 + k0 + q * 8);
            acc = __builtin_amdgcn_mfma_f32_16x16x32_bf16(af, bfr, acc, 0, 0, 0);
        }
        #pragma unroll
        for (int r = 0; r < 4; ++r)
            op[(size_t)(m0 + q * 4 + r) * 256 + col] = f2bf(acc[r]);
    }
}

// ---------------------------------------------------------------------------
// Fused pair MLP + CE (round-8 validated). Grid 256 x 512; 4 tiles of 64
// pairs per block; W2 fragments preloaded once into 32 short8 registers.
// ---------------------------------------------------------------------------
__global__ __launch_bounds__(512, 1) void pair_k(
    const unsigned short* __restrict__ A1t, const unsigned short* __restrict__ A2t,
    const float* __restrict__ b1, const unsigned short* __restrict__ W2T,
    const float* __restrict__ b2, const unsigned short* __restrict__ WfT,
    const float* __restrict__ bfv,
    const int* __restrict__ sel_b, const int* __restrict__ sel_i,
    const int* __restrict__ sel_j, const int* __restrict__ golden,
    float* __restrict__ out)
{
    __shared__ __align__(16) unsigned short sbuf[64 * H1STR];
    __shared__ __align__(16) unsigned short b1s[256];
    __shared__ float Lg[64 * 8];
    __shared__ int sidx[64 * PTILES], didx[64 * PTILES], gold[64 * PTILES];

    const int tid = threadIdx.x;
    const int w = tid >> 6;
    const int lane = tid & 63;
    const int q = lane >> 4;
    const int tx = lane & 15;
    const int m = lane & 31;
    const int hh = lane >> 5;
    const int e0 = blockIdx.x * 64 * PTILES;

    if (tid < 64 * PTILES) {
        const int e = e0 + tid;
        const int b = sel_b[e];
        sidx[tid] = b * N_PER_B + sel_i[e];
        didx[tid] = b * N_PER_B + sel_j[e];
        gold[tid] = golden[e];
    }
    if (tid < 256) b1s[tid] = f2bf(b1[tid]);

    const int pt = w & 1;
    const int cg = w >> 1;
    short8 Breg[32];
    {
        const unsigned short* bb = W2T + (size_t)(cg * 64 + m) * 256 + hh * 8;
        #pragma unroll
        for (int cc = 0; cc < 2; ++cc)
            #pragma unroll
            for (int s = 0; s < 16; ++s)
                Breg[cc * 16 + s] = *(const short8*)(bb + (size_t)cc * 32 * 256 + s * 16);
    }
    __syncthreads();

    float total = 0.f;

    for (int t = 0; t < PTILES; ++t) {
        {
            const int hw = tid >> 5;
            #pragma unroll
            for (int j = 0; j < 4; ++j) {
                const int p = j * 16 + hw;
                const unsigned short* r1 = A1t + (size_t)sidx[t * 64 + p] * 256 + m * 8;
                const unsigned short* r2 = A2t + (size_t)didx[t * 64 + p] * 256 + m * 8;
                const uint4 u1 = *(const uint4*)r1;
                const uint4 u2 = *(const uint4*)r2;
                const uint4 ub = *(const uint4*)(b1s + m * 8);
                uint2 lo2, hi2;
                lo2.x = addrelu2(u1.x, u2.x, ub.x);
                lo2.y = addrelu2(u1.y, u2.y, ub.y);
                hi2.x = addrelu2(u1.z, u2.z, ub.z);
                hi2.y = addrelu2(u1.w, u2.w, ub.w);
                unsigned short* dbase = sbuf + p * H1STR + m * 8;
                *(uint2*)(dbase) = lo2;
                *(uint2*)(dbase + 4) = hi2;
            }
        }
        __syncthreads();

        f32x16 acc0 = (f32x16)0.f;
        f32x16 acc1 = (f32x16)0.f;
        {
            const unsigned short* arow = sbuf + (size_t)(pt * 32 + m) * H1STR + hh * 8;
            #pragma unroll
            for (int s = 0; s < 16; ++s) {
                const short8 af = ld_frag(arow + s * 16);
                acc0 = __builtin_amdgcn_mfma_f32_32x32x16_bf16(af, Breg[s], acc0, 0, 0, 0);
                acc1 = __builtin_amdgcn_mfma_f32_32x32x16_bf16(af, Breg[16 + s], acc1, 0, 0, 0);
            }
        }
        __syncthreads();

        #pragma unroll
        for (int cc = 0; cc < 2; ++cc) {
            const f32x16* ap = cc ? &acc1 : &acc0;
            const int col = cg * 64 + cc * 32 + m;
            const float bv = b2[col];
            #pragma unroll
            for (int reg = 0; reg < 16; ++reg) {
                const int prow = pt * 32 + (reg & 3) + 8 * (reg >> 2) + 4 * hh;
                sbuf[prow * H1STR + col] = f2bf(fmaxf((*ap)[reg] + bv, 0.f));
            }
        }
        __syncthreads();

        if (w < 4) {
            f32x4 accL = (f32x4)0.f;
            const unsigned short* a2row = sbuf + (size_t)(w * 16 + tx) * H1STR + q * 8;
            const unsigned short* bWf = WfT + (size_t)tx * 256 + q * 8;
            #pragma unroll
            for (int s = 0; s < 8; ++s) {
                const short8 af = ld_frag(a2row + s * 32);
                const short8 bfr = *(const short8*)(bWf + s * 32);
                accL = __builtin_amdgcn_mfma_f32_16x16x32_bf16(af, bfr, accL, 0, 0, 0);
            }
            if (tx < NET) {
                const float bb = bfv[tx];
                #pragma unroll
                for (int reg = 0; reg < 4; ++reg)
                    Lg[(w * 16 + q * 4 + reg) * 8 + tx] = accL[reg] + bb;
            }
        }
        __syncthreads();

        if (tid < 64) {
            float lg[NET];
            #pragma unroll
            for (int tt = 0; tt < NET; ++tt) lg[tt] = Lg[tid * 8 + tt];
            float mx = lg[0];
            #pragma unroll
            for (int tt = 1; tt < NET; ++tt) mx = fmaxf(mx, lg[tt]);
            float s = 0.f;
            #pragma unroll
            for (int tt = 0; tt < NET; ++tt) s += expf(lg[tt] - mx);
            float ls = mx + logf(s) - lg[gold[t * 64 + tid]];
            #pragma unroll
            for (int off = 32; off >= 1; off >>= 1) ls += __shfl_xor(ls, off);
            total += ls;
        }
        __syncthreads();
    }

    if (tid == 0) atomicAdd(out, total * (1.0f / NSEL));
}

// ---------------------------------------------------------------------------
extern "C" void kernel_launch(void* const* d_in, const int* in_sizes, int n_in,
                              void* d_out, int out_size, void* d_ws, size_t ws_size,
                              hipStream_t stream) {
    (void)in_sizes; (void)n_in; (void)out_size; (void)ws_size;
    const float* x      = (const float*)d_in[0];
    const int*   eidx   = (const int*)d_in[1];
    const float* eattr  = (const float*)d_in[2];
    const float* props  = (const float*)d_in[3];
    const int*   sel_b  = (const int*)d_in[4];
    const int*   sel_i  = (const int*)d_in[5];
    const int*   sel_j  = (const int*)d_in[6];
    const int*   golden = (const int*)d_in[7];
    const float* W_prop = (const float*)d_in[8];
    const float* b_prop = (const float*)d_in[9];
    const float* W_in   = (const float*)d_in[10];
    const float* b_in   = (const float*)d_in[11];
    const float* W_msg  = (const float*)d_in[12];
    const float* b_msg  = (const float*)d_in[13];
    const float* W_upd  = (const float*)d_in[14];
    const float* b_upd  = (const float*)d_in[15];
    const float* W_add  = (const float*)d_in[16];
    const float* b_add  = (const float*)d_in[17];
    const float* W1     = (const float*)d_in[18];
    const float* b1     = (const float*)d_in[19];
    const float* W2     = (const float*)d_in[20];
    const float* b2     = (const float*)d_in[21];
    const float* W3     = (const float*)d_in[22];
    const float* b3     = (const float*)d_in[23];
    const float* W_out  = (const float*)d_in[24];
    const float* b_out  = (const float*)d_in[25];

    const size_t SEG = (size_t)BN * 256;
    unsigned short* P0   = (unsigned short*)d_ws;   // P even; final A1
    unsigned short* P1   = P0 + SEG;
    unsigned short* hA   = P1 + SEG;                // h double-buffer; final A2
    unsigned short* hB   = hA + SEG;
    unsigned short* ETc  = hB + SEG;                // [NE][256] CSR-ordered
    unsigned short* wbf  = ETc + (size_t)NE * 256;
    unsigned short* W_inT  = wbf;                   // [256][192]
    unsigned short* WmT    = wbf + 49152;
    unsigned short* WuaT   = WmT + 65536;
    unsigned short* WubT   = WuaT + 65536;
    unsigned short* W_addT = WubT + 65536;
    unsigned short* W1aT   = W_addT + 65536;
    unsigned short* W1bT   = W1aT + 65536;
    unsigned short* W2T    = W1bT + 65536;
    unsigned short* WfT    = W2T + 65536;           // [16][256]
    float* prop_add = (float*)(WfT + 4096);         // [64][256]
    float* bfv = prop_add + 64 * 256;               // [16]
    int* row_start = (int*)(bfv + 16);              // [4097]
    int2* recs     = (int2*)(row_start + 4104);     // [NE] (src,dst)
    int* epos      = (int*)(recs + NE);             // [NE]

    csr_all<<<1, 1024, 0, stream>>>(eidx, row_start, recs, epos);
    k_pre<<<577, 256, 0, stream>>>(W_in, W_msg, W_upd, W_add, W1, W2, W3, b3,
                                   W_out, b_out, props, W_prop, b_prop, b_add,
                                   b_msg, eattr, epos, wbf, WfT, bfv, prop_add,
                                   ETc, (float*)d_out);

    // round 0: h0 = relu(x@W_in+b) -> hA; P0 = h0@Wm
    fstep<<<256, 1024, 0, stream>>>(x, nullptr, nullptr, ETc, row_start, recs,
                                    W_inT, nullptr, b_in, WmT, nullptr, nullptr, nullptr,
                                    hA, P0, nullptr, 0);
    // rounds 1..3: agg(P) -> h' -> P'
    fstep<<<256, 1024, 0, stream>>>(nullptr, hA, P0, ETc, row_start, recs,
                                    WuaT, WubT, b_upd, WmT, nullptr, nullptr, nullptr,
                                    hB, P1, nullptr, 1);
    fstep<<<256, 1024, 0, stream>>>(nullptr, hB, P1, ETc, row_start, recs,
                                    WuaT, WubT, b_upd, WmT, nullptr, nullptr, nullptr,
                                    hA, P0, nullptr, 1);
    fstep<<<256, 1024, 0, stream>>>(nullptr, hA, P0, ETc, row_start, recs,
                                    WuaT, WubT, b_upd, WmT, nullptr, nullptr, nullptr,
                                    hB, P1, nullptr, 1);
    // final: agg(P1) -> h4 -> embg -> A1 (P0), A2 (hA)
    fstep<<<256, 1024, 0, stream>>>(nullptr, hB, P1, ETc, row_start, recs,
                                    WuaT, WubT, b_upd, W_addT, prop_add, W1aT, W1bT,
                                    nullptr, P0, hA, 2);

    pair_k<<<256, 512, 0, stream>>>(P0, hA, b1, W2T, b2, WfT, bfv,
                                    sel_b, sel_i, sel_j, golden, (float*)d_out);
}

// Round 11
// 258.309 us; speedup vs baseline: 1.3731x; 1.3731x over previous
//
#include <hip/hip_runtime.h>
#include <math.h>

#define BN 4096
#define N_PER_B 64
#define NE 16384
#define NSEL 65536
#define NET 5
#define PD 64
#define H1STR 260   // pair LDS stride (shorts)
#define FSTR 264    // fstep LDS stride (shorts)
#define PTILES 4

typedef float f32x4 __attribute__((ext_vector_type(4)));
typedef float f32x16 __attribute__((ext_vector_type(16)));
typedef short short8 __attribute__((ext_vector_type(8)));
typedef short short4v __attribute__((ext_vector_type(4)));

__device__ __forceinline__ unsigned short f2bf(float f) {
    unsigned int u = __builtin_bit_cast(unsigned int, f);
    u += 0x7fff + ((u >> 16) & 1);          // RNE
    return (unsigned short)(u >> 16);
}
__device__ __forceinline__ float bf_lo(unsigned int u) {
    return __builtin_bit_cast(float, u << 16);
}
__device__ __forceinline__ float bf_hi(unsigned int u) {
    return __builtin_bit_cast(float, u & 0xffff0000u);
}
__device__ __forceinline__ unsigned int pack2(float a, float b) {
    return (unsigned)f2bf(a) | ((unsigned)f2bf(b) << 16);
}
__device__ __forceinline__ short8 ld_frag(const unsigned short* p) {
    const short4v lo = *(const short4v*)(p);
    const short4v hi = *(const short4v*)(p + 4);
    return __builtin_shufflevector(lo, hi, 0, 1, 2, 3, 4, 5, 6, 7);
}
__device__ __forceinline__ unsigned int addrelu2(unsigned int a, unsigned int b, unsigned int c) {
    const float lo = fmaxf(bf_lo(a) + bf_lo(b) + bf_lo(c), 0.f);
    const float hi = fmaxf(bf_hi(a) + bf_hi(b) + bf_hi(c), 0.f);
    return pack2(lo, hi);
}

// ---------------------------------------------------------------------------
// Single-block CSR build: LDS hist -> scan -> scatter.
// srcs[pos] = src node of the edge in CSR slot pos; epos[e] = slot of edge e.
// ---------------------------------------------------------------------------
__global__ __launch_bounds__(1024) void csr_all(const int* __restrict__ eidx,
                                                int* __restrict__ row_start,
                                                int* __restrict__ srcs,
                                                int* __restrict__ epos)
{
    __shared__ int sdeg[4096];
    __shared__ int scan1[1024];
    const int tid = threadIdx.x;
    #pragma unroll
    for (int i = 0; i < 4; ++i) sdeg[tid * 4 + i] = 0;
    __syncthreads();
    #pragma unroll
    for (int r = 0; r < NE / 1024; ++r)
        atomicAdd(&sdeg[eidx[NE + r * 1024 + tid]], 1);
    __syncthreads();
    const int l0 = sdeg[tid * 4 + 0];
    const int l1 = sdeg[tid * 4 + 1];
    const int l2 = sdeg[tid * 4 + 2];
    const int l3 = sdeg[tid * 4 + 3];
    scan1[tid] = l0 + l1 + l2 + l3;
    __syncthreads();
    for (int off = 1; off < 1024; off <<= 1) {
        const int v = scan1[tid];
        const int add = (tid >= off) ? scan1[tid - off] : 0;
        __syncthreads();
        scan1[tid] = v + add;
        __syncthreads();
    }
    const int base = (tid == 0) ? 0 : scan1[tid - 1];
    row_start[tid * 4 + 0] = base;
    row_start[tid * 4 + 1] = base + l0;
    row_start[tid * 4 + 2] = base + l0 + l1;
    row_start[tid * 4 + 3] = base + l0 + l1 + l2;
    sdeg[tid * 4 + 0] = base;
    sdeg[tid * 4 + 1] = base + l0;
    sdeg[tid * 4 + 2] = base + l0 + l1;
    sdeg[tid * 4 + 3] = base + l0 + l1 + l2;
    if (tid == 0) row_start[4096] = NE;
    __syncthreads();
    #pragma unroll
    for (int r = 0; r < NE / 1024; ++r) {
        const int e = r * 1024 + tid;
        const int d = eidx[NE + e];
        const int s = eidx[e];
        const int pos = atomicAdd(&sdeg[d], 1);
        srcs[pos] = s;
        epos[e] = pos;
    }
}

// ---------------------------------------------------------------------------
// Preamble mega-kernel:
//  [0,128)    weight convert/transpose fp32 [K][256] -> bf16 [256][K]
//  [128,192)  prop_add  (blk 128 also zeroes d_out)
//  [192,449)  Wfold = W3@W_out -> bf16 WfT[16][256] + bfv
//  [449,513)  eaP[slot][8] = eattr_e[0..4]  (CSR-slot order, 32B stride)
// ---------------------------------------------------------------------------
__global__ __launch_bounds__(256) void k_pre(
    const float* __restrict__ W_in, const float* __restrict__ W_msg,
    const float* __restrict__ W_upd, const float* __restrict__ W_add,
    const float* __restrict__ W1, const float* __restrict__ W2,
    const float* __restrict__ W3, const float* __restrict__ b3,
    const float* __restrict__ W_out, const float* __restrict__ b_out,
    const float* __restrict__ props, const float* __restrict__ W_prop,
    const float* __restrict__ b_prop, const float* __restrict__ b_add,
    const float* __restrict__ eattr, const int* __restrict__ epos,
    unsigned short* __restrict__ wbf, unsigned short* __restrict__ WfT,
    float* __restrict__ bfv, float* __restrict__ prop_add,
    float* __restrict__ eaP, float* __restrict__ dout)
{
    __shared__ __align__(16) char smem[16704];
    const int blk = blockIdx.x;
    const int tid = threadIdx.x;

    if (blk < 128) {                          // ---- weight convert/transpose
        float (*s)[65] = (float(*)[65])smem;
        const int wsel = blk >> 4;
        const int sub = blk & 15;
        const float* src; unsigned short* dst; int K = 256;
        switch (wsel) {
            case 0: src = W_in;              dst = wbf;                         K = 192; break;
            case 1: src = W_msg;             dst = wbf + 49152;                 break;
            case 2: src = W_upd;             dst = wbf + 49152 + 65536;         break;
            case 3: src = W_upd + 256 * 256; dst = wbf + 49152 + 2 * 65536;     break;
            case 4: src = W_add;             dst = wbf + 49152 + 3 * 65536;     break;
            case 5: src = W1;                dst = wbf + 49152 + 4 * 65536;     break;
            case 6: src = W1 + 256 * 256;    dst = wbf + 49152 + 5 * 65536;     break;
            default: src = W2;               dst = wbf + 49152 + 6 * 65536;     break;
        }
        const int k0 = (sub >> 2) * 64;
        const int n0 = (sub & 3) * 64;
        if (k0 >= K) return;
        const int tn = tid & 63;
        const int tg = tid >> 6;
        #pragma unroll
        for (int i = 0; i < 16; ++i) {
            const int kk = tg * 16 + i;
            s[kk][tn] = src[(size_t)(k0 + kk) * 256 + n0 + tn];
        }
        __syncthreads();
        #pragma unroll
        for (int i = 0; i < 16; ++i) {
            const int nn = tg * 16 + i;
            dst[(size_t)(n0 + nn) * K + k0 + tn] = f2bf(s[tn][nn]);
        }
    } else if (blk < 192) {                   // ---- prop_add (+ d_out zero)
        const int b = blk - 128;
        if (b == 0 && tid == 0) *dout = 0.f;
        const float pv = props[b];
        float acc = b_add[tid];
        #pragma unroll 8
        for (int p = 0; p < PD; ++p) {
            const float e = fmaf(pv, W_prop[p], b_prop[p]);
            acc = fmaf(e, W_add[(256 + p) * 256 + tid], acc);
        }
        prop_add[b * 256 + tid] = acc;
    } else if (blk < 449) {                   // ---- Wfold + bfv
        float* part = (float*)smem;           // [4][NET]
        const int cb = blk - 192;             // 0..256
        float acc[NET] = {0.f, 0.f, 0.f, 0.f, 0.f};
        #pragma unroll
        for (int rep = 0; rep < 2; ++rep) {
            const int j = rep * 256 + tid;
            const float wv = (cb < 256) ? W3[(size_t)cb * 512 + j] : b3[j];
            #pragma unroll
            for (int t = 0; t < NET; ++t) acc[t] = fmaf(wv, W_out[j * NET + t], acc[t]);
        }
        #pragma unroll
        for (int t = 0; t < NET; ++t)
            for (int off = 32; off >= 1; off >>= 1) acc[t] += __shfl_down(acc[t], off);
        if ((tid & 63) == 0) {
            #pragma unroll
            for (int t = 0; t < NET; ++t) part[(tid >> 6) * NET + t] = acc[t];
        }
        __syncthreads();
        if (tid == 0) {
            float s[NET];
            #pragma unroll
            for (int t = 0; t < NET; ++t)
                s[t] = part[t] + part[NET + t] + part[2 * NET + t] + part[3 * NET + t];
            if (cb < 256) {
                #pragma unroll
                for (int t = 0; t < NET; ++t) WfT[t * 256 + cb] = f2bf(s[t]);
                #pragma unroll
                for (int t = NET; t < 16; ++t) WfT[t * 256 + cb] = 0;
            } else {
                #pragma unroll
                for (int t = 0; t < NET; ++t) bfv[t] = s[t] + b_out[t];
            }
        }
    } else {                                  // ---- pack eattr into CSR order
        const int e = (blk - 449) * 256 + tid;
        const int pos = epos[e];
        const float a0 = eattr[e * 5 + 0];
        const float a1 = eattr[e * 5 + 1];
        const float a2 = eattr[e * 5 + 2];
        const float a3 = eattr[e * 5 + 3];
        const float a4 = eattr[e * 5 + 4];
        float* dst = eaP + (size_t)pos * 8;
        float4 v; v.x = a0; v.y = a1; v.z = a2; v.w = a3;
        *(float4*)dst = v;
        dst[4] = a4;
    }
}

// ---------------------------------------------------------------------------
// Fused node step. 1024 threads = 16 waves; 16 node-rows/block (grid 256).
// Phase A (modes 1,2): wave-per-node agg, edge term computed on the fly:
//   agg[n] = sum_e relu(P[src_e] + eattr_e@Wme + b_msg)
//   (lane keeps its 4 Wme columns + b_msg in 24 VGPRs; eaP is slot-indexed,
//    so only srcs[slot] -> P-row is a dependent chain)
// Phase B: act = relu(h@Wua + agg@Wub + b)   (mode 0: relu(x@W_in+b))
// Phase C: P = act@Wm (modes 0,1) | embg=act@W_add+prop -> A1,A2 (mode 2)
// ---------------------------------------------------------------------------
__global__ __launch_bounds__(1024) void fstep(
    const float* __restrict__ x, const unsigned short* __restrict__ hbuf,
    const unsigned short* __restrict__ Pin,
    const int* __restrict__ row_start, const int* __restrict__ srcs,
    const float* __restrict__ eaP, const float* __restrict__ Wme,
    const float* __restrict__ bmsg,
    const unsigned short* __restrict__ WaT, const unsigned short* __restrict__ WbT,
    const float* __restrict__ bias1,
    const unsigned short* __restrict__ Wp2T, const float* __restrict__ prop_add,
    const unsigned short* __restrict__ W1aT, const unsigned short* __restrict__ W1bT,
    unsigned short* __restrict__ hout, unsigned short* __restrict__ out1,
    unsigned short* __restrict__ out2, int mode)
{
    __shared__ __align__(16) unsigned short Hg[16 * FSTR];   // staged h tile
    __shared__ __align__(16) unsigned short Ag[16 * FSTR];   // agg tile (bf16)
    __shared__ __align__(16) unsigned short Hs[16 * FSTR];   // act
    __shared__ __align__(16) unsigned short H2s[16 * FSTR];  // embg (mode 2)
    const int tid = threadIdx.x;
    const int w = tid >> 6;          // 0..15
    const int lane = tid & 63;
    const int q = lane >> 4;
    const int tx = lane & 15;
    const int m0 = blockIdx.x * 16;
    const int col = w * 16 + tx;

    // ---- phase A: stage h tile + wave-per-node agg (modes 1,2)
    if (mode != 0) {
        {
            const int r = tid >> 6;
            const int c4 = (tid & 63) * 4;
            *(uint2*)&Hg[r * FSTR + c4] =
                *(const uint2*)(hbuf + (size_t)(m0 + r) * 256 + c4);
        }
        {
            const int c = lane * 4;
            const float4 w0 = *(const float4*)(Wme + 0 * 256 + c);
            const float4 w1 = *(const float4*)(Wme + 1 * 256 + c);
            const float4 w2 = *(const float4*)(Wme + 2 * 256 + c);
            const float4 w3 = *(const float4*)(Wme + 3 * 256 + c);
            const float4 w4 = *(const float4*)(Wme + 4 * 256 + c);
            const float4 bm = *(const float4*)(bmsg + c);
            const int node = m0 + w;
            const int beg = row_start[node];
            const int end = row_start[node + 1];
            float a0 = 0.f, a1 = 0.f, a2 = 0.f, a3 = 0.f;
            int idx = beg;
            for (; idx + 2 <= end; idx += 2) {
                const int s0 = srcs[idx];
                const int s1 = srcs[idx + 1];
                const float4 e0 = *(const float4*)(eaP + (size_t)idx * 8);
                const float  e0w = eaP[(size_t)idx * 8 + 4];
                const float4 e1 = *(const float4*)(eaP + (size_t)(idx + 1) * 8);
                const float  e1w = eaP[(size_t)(idx + 1) * 8 + 4];
                const uint2 p0 = *(const uint2*)(Pin + (size_t)s0 * 256 + c);
                const uint2 p1 = *(const uint2*)(Pin + (size_t)s1 * 256 + c);
                float tx0 = bm.x, ty0 = bm.y, tz0 = bm.z, tw0 = bm.w;
                tx0 = fmaf(e0.x, w0.x, tx0); ty0 = fmaf(e0.x, w0.y, ty0); tz0 = fmaf(e0.x, w0.z, tz0); tw0 = fmaf(e0.x, w0.w, tw0);
                tx0 = fmaf(e0.y, w1.x, tx0); ty0 = fmaf(e0.y, w1.y, ty0); tz0 = fmaf(e0.y, w1.z, tz0); tw0 = fmaf(e0.y, w1.w, tw0);
                tx0 = fmaf(e0.z, w2.x, tx0); ty0 = fmaf(e0.z, w2.y, ty0); tz0 = fmaf(e0.z, w2.z, tz0); tw0 = fmaf(e0.z, w2.w, tw0);
                tx0 = fmaf(e0.w, w3.x, tx0); ty0 = fmaf(e0.w, w3.y, ty0); tz0 = fmaf(e0.w, w3.z, tz0); tw0 = fmaf(e0.w, w3.w, tw0);
                tx0 = fmaf(e0w,  w4.x, tx0); ty0 = fmaf(e0w,  w4.y, ty0); tz0 = fmaf(e0w,  w4.z, tz0); tw0 = fmaf(e0w,  w4.w, tw0);
                a0 += fmaxf(bf_lo(p0.x) + tx0, 0.f);
                a1 += fmaxf(bf_hi(p0.x) + ty0, 0.f);
                a2 += fmaxf(bf_lo(p0.y) + tz0, 0.f);
                a3 += fmaxf(bf_hi(p0.y) + tw0, 0.f);
                float tx1 = bm.x, ty1 = bm.y, tz1 = bm.z, tw1 = bm.w;
                tx1 = fmaf(e1.x, w0.x, tx1); ty1 = fmaf(e1.x, w0.y, ty1); tz1 = fmaf(e1.x, w0.z, tz1); tw1 = fmaf(e1.x, w0.w, tw1);
                tx1 = fmaf(e1.y, w1.x, tx1); ty1 = fmaf(e1.y, w1.y, ty1); tz1 = fmaf(e1.y, w1.z, tz1); tw1 = fmaf(e1.y, w1.w, tw1);
                tx1 = fmaf(e1.z, w2.x, tx1); ty1 = fmaf(e1.z, w2.y, ty1); tz1 = fmaf(e1.z, w2.z, tz1); tw1 = fmaf(e1.z, w2.w, tw1);
                tx1 = fmaf(e1.w, w3.x, tx1); ty1 = fmaf(e1.w, w3.y, ty1); tz1 = fmaf(e1.w, w3.z, tz1); tw1 = fmaf(e1.w, w3.w, tw1);
                tx1 = fmaf(e1w,  w4.x, tx1); ty1 = fmaf(e1w,  w4.y, ty1); tz1 = fmaf(e1w,  w4.z, tz1); tw1 = fmaf(e1w,  w4.w, tw1);
                a0 += fmaxf(bf_lo(p1.x) + tx1, 0.f);
                a1 += fmaxf(bf_hi(p1.x) + ty1, 0.f);
                a2 += fmaxf(bf_lo(p1.y) + tz1, 0.f);
                a3 += fmaxf(bf_hi(p1.y) + tw1, 0.f);
            }
            if (idx < end) {
                const int s0 = srcs[idx];
                const float4 e0 = *(const float4*)(eaP + (size_t)idx * 8);
                const float  e0w = eaP[(size_t)idx * 8 + 4];
                const uint2 p0 = *(const uint2*)(Pin + (size_t)s0 * 256 + c);
                float tx0 = bm.x, ty0 = bm.y, tz0 = bm.z, tw0 = bm.w;
                tx0 = fmaf(e0.x, w0.x, tx0); ty0 = fmaf(e0.x, w0.y, ty0); tz0 = fmaf(e0.x, w0.z, tz0); tw0 = fmaf(e0.x, w0.w, tw0);
                tx0 = fmaf(e0.y, w1.x, tx0); ty0 = fmaf(e0.y, w1.y, ty0); tz0 = fmaf(e0.y, w1.z, tz0); tw0 = fmaf(e0.y, w1.w, tw0);
                tx0 = fmaf(e0.z, w2.x, tx0); ty0 = fmaf(e0.z, w2.y, ty0); tz0 = fmaf(e0.z, w2.z, tz0); tw0 = fmaf(e0.z, w2.w, tw0);
                tx0 = fmaf(e0.w, w3.x, tx0); ty0 = fmaf(e0.w, w3.y, ty0); tz0 = fmaf(e0.w, w3.z, tz0); tw0 = fmaf(e0.w, w3.w, tw0);
                tx0 = fmaf(e0w,  w4.x, tx0); ty0 = fmaf(e0w,  w4.y, ty0); tz0 = fmaf(e0w,  w4.z, tz0); tw0 = fmaf(e0w,  w4.w, tw0);
                a0 += fmaxf(bf_lo(p0.x) + tx0, 0.f);
                a1 += fmaxf(bf_hi(p0.x) + ty0, 0.f);
                a2 += fmaxf(bf_lo(p0.y) + tz0, 0.f);
                a3 += fmaxf(bf_hi(p0.y) + tw0, 0.f);
            }
            uint2 o; o.x = pack2(a0, a1); o.y = pack2(a2, a3);
            *(uint2*)&Ag[w * FSTR + c] = o;
        }
        __syncthreads();
    }

    // ---- phase B: act = relu(A@W + b), wave w -> one 16-col tile
    f32x4 acc = (f32x4)0.f;
    if (mode == 0) {
        #pragma unroll
        for (int s = 0; s < 6; ++s) {
            const int k0 = s * 32;
            const float* ap = x + (size_t)(m0 + tx) * 192 + k0 + q * 8;
            const float4 v0 = *(const float4*)ap;
            const float4 v1 = *(const float4*)(ap + 4);
            short8 af;
            af[0] = (short)f2bf(v0.x); af[1] = (short)f2bf(v0.y);
            af[2] = (short)f2bf(v0.z); af[3] = (short)f2bf(v0.w);
            af[4] = (short)f2bf(v1.x); af[5] = (short)f2bf(v1.y);
            af[6] = (short)f2bf(v1.z); af[7] = (short)f2bf(v1.w);
            const short8 bfr = *(const short8*)(WaT + (size_t)col * 192 + k0 + q * 8);
            acc = __builtin_amdgcn_mfma_f32_16x16x32_bf16(af, bfr, acc, 0, 0, 0);
        }
    } else {
        #pragma unroll
        for (int s = 0; s < 8; ++s) {
            const int k0 = s * 32;
            const short8 af = *(const short8*)&Hg[tx * FSTR + k0 + q * 8];
            const short8 bfr = *(const short8*)(WaT + (size_t)col * 256 + k0 + q * 8);
            acc = __builtin_amdgcn_mfma_f32_16x16x32_bf16(af, bfr, acc, 0, 0, 0);
        }
        #pragma unroll
        for (int s = 0; s < 8; ++s) {
            const int k0 = s * 32;
            const short8 af = *(const short8*)&Ag[tx * FSTR + k0 + q * 8];
            const short8 bfr = *(const short8*)(WbT + (size_t)col * 256 + k0 + q * 8);
            acc = __builtin_amdgcn_mfma_f32_16x16x32_bf16(af, bfr, acc, 0, 0, 0);
        }
    }
    {
        const float bv = bias1[col];
        #pragma unroll
        for (int r = 0; r < 4; ++r) {
            const int row = q * 4 + r;
            const unsigned short us = f2bf(fmaxf(acc[r] + bv, 0.f));
            Hs[row * FSTR + col] = us;
            if (mode < 2) hout[(size_t)(m0 + row) * 256 + col] = us;
        }
    }
    __syncthreads();

    // ---- phase C: act @ Wp2
    acc = (f32x4)0.f;
    #pragma unroll
    for (int s = 0; s < 8; ++s) {
        const int k0 = s * 32;
        const short8 af = *(const short8*)&Hs[tx * FSTR + k0 + q * 8];
        const short8 bfr = *(const short8*)(Wp2T + (size_t)col * 256 + k0 + q * 8);
        acc = __builtin_amdgcn_mfma_f32_16x16x32_bf16(af, bfr, acc, 0, 0, 0);
    }
    if (mode < 2) {
        #pragma unroll
        for (int r = 0; r < 4; ++r)
            out1[(size_t)(m0 + q * 4 + r) * 256 + col] = f2bf(acc[r]);
        return;
    }
    {
        const float pv = prop_add[(m0 >> 6) * 256 + col];
        #pragma unroll
        for (int r = 0; r < 4; ++r)
            H2s[(q * 4 + r) * FSTR + col] = f2bf(acc[r] + pv);
    }
    __syncthreads();

    // ---- phase 2b: A1 = embg@W1a, A2 = embg@W1b
    for (int which = 0; which < 2; ++which) {
        const unsigned short* WT = which ? W1bT : W1aT;
        unsigned short* op = which ? out2 : out1;
        acc = (f32x4)0.f;
        #pragma unroll
        for (int s = 0; s < 8; ++s) {
            const int k0 = s * 32;
            const short8 af = *(const short8*)&H2s[tx * FSTR + k0 + q * 8];
            const short8 bfr = *(const short8*)(WT + (size_t)col * 256 + k0 + q * 8);
            acc = __builtin_amdgcn_mfma_f32_16x16x32_bf16(af, bfr, acc, 0, 0, 0);
        }
        #pragma unroll
        for (int r = 0; r < 4; ++r)
            op[(size_t)(m0 + q * 4 + r) * 256 + col] = f2bf(acc[r]);
    }
}

// ---------------------------------------------------------------------------
// Fused pair MLP + CE (validated). Grid 256 x 512; 4 tiles of 64 pairs per
// block; W2 fragments preloaded once into 32 short8 registers.
// ---------------------------------------------------------------------------
__global__ __launch_bounds__(512, 1) void pair_k(
    const unsigned short* __restrict__ A1t, const unsigned short* __restrict__ A2t,
    const float* __restrict__ b1, const unsigned short* __restrict__ W2T,
    const float* __restrict__ b2, const unsigned short* __restrict__ WfT,
    const float* __restrict__ bfv,
    const int* __restrict__ sel_b, const int* __restrict__ sel_i,
    const int* __restrict__ sel_j, const int* __restrict__ golden,
    float* __restrict__ out)
{
    __shared__ __align__(16) unsigned short sbuf[64 * H1STR];
    __shared__ __align__(16) unsigned short b1s[256];
    __shared__ float Lg[64 * 8];
    __shared__ int sidx[64 * PTILES], didx[64 * PTILES], gold[64 * PTILES];

    const int tid = threadIdx.x;
    const int w = tid >> 6;
    const int lane = tid & 63;
    const int q = lane >> 4;
    const int tx = lane & 15;
    const int m = lane & 31;
    const int hh = lane >> 5;
    const int e0 = blockIdx.x * 64 * PTILES;

    if (tid < 64 * PTILES) {
        const int e = e0 + tid;
        const int b = sel_b[e];
        sidx[tid] = b * N_PER_B + sel_i[e];
        didx[tid] = b * N_PER_B + sel_j[e];
        gold[tid] = golden[e];
    }
    if (tid < 256) b1s[tid] = f2bf(b1[tid]);

    const int pt = w & 1;
    const int cg = w >> 1;
    short8 Breg[32];
    {
        const unsigned short* bb = W2T + (size_t)(cg * 64 + m) * 256 + hh * 8;
        #pragma unroll
        for (int cc = 0; cc < 2; ++cc)
            #pragma unroll
            for (int s = 0; s < 16; ++s)
                Breg[cc * 16 + s] = *(const short8*)(bb + (size_t)cc * 32 * 256 + s * 16);
    }
    __syncthreads();

    float total = 0.f;

    for (int t = 0; t < PTILES; ++t) {
        {
            const int hw = tid >> 5;
            #pragma unroll
            for (int j = 0; j < 4; ++j) {
                const int p = j * 16 + hw;
                const unsigned short* r1 = A1t + (size_t)sidx[t * 64 + p] * 256 + m * 8;
                const unsigned short* r2 = A2t + (size_t)didx[t * 64 + p] * 256 + m * 8;
                const uint4 u1 = *(const uint4*)r1;
                const uint4 u2 = *(const uint4*)r2;
                const uint4 ub = *(const uint4*)(b1s + m * 8);
                uint2 lo2, hi2;
                lo2.x = addrelu2(u1.x, u2.x, ub.x);
                lo2.y = addrelu2(u1.y, u2.y, ub.y);
                hi2.x = addrelu2(u1.z, u2.z, ub.z);
                hi2.y = addrelu2(u1.w, u2.w, ub.w);
                unsigned short* dbase = sbuf + p * H1STR + m * 8;
                *(uint2*)(dbase) = lo2;
                *(uint2*)(dbase + 4) = hi2;
            }
        }
        __syncthreads();

        f32x16 acc0 = (f32x16)0.f;
        f32x16 acc1 = (f32x16)0.f;
        {
            const unsigned short* arow = sbuf + (size_t)(pt * 32 + m) * H1STR + hh * 8;
            #pragma unroll
            for (int s = 0; s < 16; ++s) {
                const short8 af = ld_frag(arow + s * 16);
                acc0 = __builtin_amdgcn_mfma_f32_32x32x16_bf16(af, Breg[s], acc0, 0, 0, 0);
                acc1 = __builtin_amdgcn_mfma_f32_32x32x16_bf16(af, Breg[16 + s], acc1, 0, 0, 0);
            }
        }
        __syncthreads();

        #pragma unroll
        for (int cc = 0; cc < 2; ++cc) {
            const f32x16* ap = cc ? &acc1 : &acc0;
            const int col = cg * 64 + cc * 32 + m;
            const float bv = b2[col];
            #pragma unroll
            for (int reg = 0; reg < 16; ++reg) {
                const int prow = pt * 32 + (reg & 3) + 8 * (reg >> 2) + 4 * hh;
                sbuf[prow * H1STR + col] = f2bf(fmaxf((*ap)[reg] + bv, 0.f));
            }
        }
        __syncthreads();

        if (w < 4) {
            f32x4 accL = (f32x4)0.f;
            const unsigned short* a2row = sbuf + (size_t)(w * 16 + tx) * H1STR + q * 8;
            const unsigned short* bWf = WfT + (size_t)tx * 256 + q * 8;
            #pragma unroll
            for (int s = 0; s < 8; ++s) {
                const short8 af = ld_frag(a2row + s * 32);
                const short8 bfr = *(const short8*)(bWf + s * 32);
                accL = __builtin_amdgcn_mfma_f32_16x16x32_bf16(af, bfr, accL, 0, 0, 0);
            }
            if (tx < NET) {
                const float bb = bfv[tx];
                #pragma unroll
                for (int reg = 0; reg < 4; ++reg)
                    Lg[(w * 16 + q * 4 + reg) * 8 + tx] = accL[reg] + bb;
            }
        }
        __syncthreads();

        if (tid < 64) {
            float lg[NET];
            #pragma unroll
            for (int tt = 0; tt < NET; ++tt) lg[tt] = Lg[tid * 8 + tt];
            float mx = lg[0];
            #pragma unroll
            for (int tt = 1; tt < NET; ++tt) mx = fmaxf(mx, lg[tt]);
            float s = 0.f;
            #pragma unroll
            for (int tt = 0; tt < NET; ++tt) s += expf(lg[tt] - mx);
            float ls = mx + logf(s) - lg[gold[t * 64 + tid]];
            #pragma unroll
            for (int off = 32; off >= 1; off >>= 1) ls += __shfl_xor(ls, off);
            total += ls;
        }
        __syncthreads();
    }

    if (tid == 0) atomicAdd(out, total * (1.0f / NSEL));
}

// ---------------------------------------------------------------------------
extern "C" void kernel_launch(void* const* d_in, const int* in_sizes, int n_in,
                              void* d_out, int out_size, void* d_ws, size_t ws_size,
                              hipStream_t stream) {
    (void)in_sizes; (void)n_in; (void)out_size; (void)ws_size;
    const float* x      = (const float*)d_in[0];
    const int*   eidx   = (const int*)d_in[1];
    const float* eattr  = (const float*)d_in[2];
    const float* props  = (const float*)d_in[3];
    const int*   sel_b  = (const int*)d_in[4];
    const int*   sel_i  = (const int*)d_in[5];
    const int*   sel_j  = (const int*)d_in[6];
    const int*   golden = (const int*)d_in[7];
    const float* W_prop = (const float*)d_in[8];
    const float* b_prop = (const float*)d_in[9];
    const float* W_in   = (const float*)d_in[10];
    const float* b_in   = (const float*)d_in[11];
    const float* W_msg  = (const float*)d_in[12];
    const float* b_msg  = (const float*)d_in[13];
    const float* W_upd  = (const float*)d_in[14];
    const float* b_upd  = (const float*)d_in[15];
    const float* W_add  = (const float*)d_in[16];
    const float* b_add  = (const float*)d_in[17];
    const float* W1     = (const float*)d_in[18];
    const float* b1     = (const float*)d_in[19];
    const float* W2     = (const float*)d_in[20];
    const float* b2     = (const float*)d_in[21];
    const float* W3     = (const float*)d_in[22];
    const float* b3     = (const float*)d_in[23];
    const float* W_out  = (const float*)d_in[24];
    const float* b_out  = (const float*)d_in[25];

    const size_t SEG = (size_t)BN * 256;
    unsigned short* P0   = (unsigned short*)d_ws;   // P even; final A1
    unsigned short* P1   = P0 + SEG;
    unsigned short* hA   = P1 + SEG;                // h double-buffer; final A2
    unsigned short* hB   = hA + SEG;
    unsigned short* wbf  = hB + SEG;
    unsigned short* W_inT  = wbf;                   // [256][192]
    unsigned short* WmT    = wbf + 49152;
    unsigned short* WuaT   = WmT + 65536;
    unsigned short* WubT   = WuaT + 65536;
    unsigned short* W_addT = WubT + 65536;
    unsigned short* W1aT   = W_addT + 65536;
    unsigned short* W1bT   = W1aT + 65536;
    unsigned short* W2T    = W1bT + 65536;
    unsigned short* WfT    = W2T + 65536;           // [16][256]
    float* prop_add = (float*)(WfT + 4096);         // [64][256]
    float* bfv  = prop_add + 64 * 256;              // [16]
    float* eaP  = bfv + 16;                         // [NE][8] CSR-slot order
    int* row_start = (int*)(eaP + (size_t)NE * 8);  // [4097]
    int* srcs      = row_start + 4104;              // [NE]
    int* epos      = srcs + NE;                     // [NE]

    csr_all<<<1, 1024, 0, stream>>>(eidx, row_start, srcs, epos);
    k_pre<<<513, 256, 0, stream>>>(W_in, W_msg, W_upd, W_add, W1, W2, W3, b3,
                                   W_out, b_out, props, W_prop, b_prop, b_add,
                                   eattr, epos, wbf, WfT, bfv, prop_add,
                                   eaP, (float*)d_out);

    const float* Wme = W_msg + 256 * 256;
    // round 0: h0 = relu(x@W_in+b) -> hA; P0 = h0@Wm
    fstep<<<256, 1024, 0, stream>>>(x, nullptr, nullptr, row_start, srcs, eaP, Wme, b_msg,
                                    W_inT, nullptr, b_in, WmT, nullptr, nullptr, nullptr,
                                    hA, P0, nullptr, 0);
    // rounds 1..3: agg(P) -> h' -> P'
    fstep<<<256, 1024, 0, stream>>>(nullptr, hA, P0, row_start, srcs, eaP, Wme, b_msg,
                                    WuaT, WubT, b_upd, WmT, nullptr, nullptr, nullptr,
                                    hB, P1, nullptr, 1);
    fstep<<<256, 1024, 0, stream>>>(nullptr, hB, P1, row_start, srcs, eaP, Wme, b_msg,
                                    WuaT, WubT, b_upd, WmT, nullptr, nullptr, nullptr,
                                    hA, P0, nullptr, 1);
    fstep<<<256, 1024, 0, stream>>>(nullptr, hA, P0, row_start, srcs, eaP, Wme, b_msg,
                                    WuaT, WubT, b_upd, WmT, nullptr, nullptr, nullptr,
                                    hB, P1, nullptr, 1);
    // final: agg(P1) -> h4 -> embg -> A1 (P0), A2 (hA)
    fstep<<<256, 1024, 0, stream>>>(nullptr, hB, P1, row_start, srcs, eaP, Wme, b_msg,
                                    WuaT, WubT, b_upd, W_addT, prop_add, W1aT, W1bT,
                                    nullptr, P0, hA, 2);

    pair_k<<<256, 512, 0, stream>>>(P0, hA, b1, W2T, b2, WfT, bfv,
                                    sel_b, sel_i, sel_j, golden, (float*)d_out);
}

// Round 12
// 256.504 us; speedup vs baseline: 1.3827x; 1.0070x over previous
//
#include <hip/hip_runtime.h>
#include <math.h>

#define BN 4096
#define N_PER_B 64
#define NE 16384
#define NSEL 65536
#define NET 5
#define PD 64
#define H1STR 260   // pair LDS stride (shorts)
#define FSTR 264    // fstep LDS stride (shorts)
#define PTILES 4

typedef float f32x4 __attribute__((ext_vector_type(4)));
typedef float f32x16 __attribute__((ext_vector_type(16)));
typedef short short8 __attribute__((ext_vector_type(8)));
typedef short short4v __attribute__((ext_vector_type(4)));

__device__ __forceinline__ unsigned short f2bf(float f) {
    unsigned int u = __builtin_bit_cast(unsigned int, f);
    u += 0x7fff + ((u >> 16) & 1);          // RNE
    return (unsigned short)(u >> 16);
}
__device__ __forceinline__ float bf_lo(unsigned int u) {
    return __builtin_bit_cast(float, u << 16);
}
__device__ __forceinline__ float bf_hi(unsigned int u) {
    return __builtin_bit_cast(float, u & 0xffff0000u);
}
__device__ __forceinline__ unsigned int pack2(float a, float b) {
    return (unsigned)f2bf(a) | ((unsigned)f2bf(b) << 16);
}
__device__ __forceinline__ short8 ld_frag(const unsigned short* p) {
    const short4v lo = *(const short4v*)(p);
    const short4v hi = *(const short4v*)(p + 4);
    return __builtin_shufflevector(lo, hi, 0, 1, 2, 3, 4, 5, 6, 7);
}
__device__ __forceinline__ unsigned int addrelu2(unsigned int a, unsigned int b, unsigned int c) {
    const float lo = fmaxf(bf_lo(a) + bf_lo(b) + bf_lo(c), 0.f);
    const float hi = fmaxf(bf_hi(a) + bf_hi(b) + bf_hi(c), 0.f);
    return pack2(lo, hi);
}

// ---------------------------------------------------------------------------
// Single-block CSR build: LDS hist -> scan -> scatter.
// srcs[pos] = src node of the edge in CSR slot pos; epos[e] = slot of edge e.
// ---------------------------------------------------------------------------
__global__ __launch_bounds__(1024) void csr_all(const int* __restrict__ eidx,
                                                int* __restrict__ row_start,
                                                int* __restrict__ srcs,
                                                int* __restrict__ epos)
{
    __shared__ int sdeg[4096];
    __shared__ int scan1[1024];
    const int tid = threadIdx.x;
    #pragma unroll
    for (int i = 0; i < 4; ++i) sdeg[tid * 4 + i] = 0;
    __syncthreads();
    #pragma unroll
    for (int r = 0; r < NE / 1024; ++r)
        atomicAdd(&sdeg[eidx[NE + r * 1024 + tid]], 1);
    __syncthreads();
    const int l0 = sdeg[tid * 4 + 0];
    const int l1 = sdeg[tid * 4 + 1];
    const int l2 = sdeg[tid * 4 + 2];
    const int l3 = sdeg[tid * 4 + 3];
    scan1[tid] = l0 + l1 + l2 + l3;
    __syncthreads();
    for (int off = 1; off < 1024; off <<= 1) {
        const int v = scan1[tid];
        const int add = (tid >= off) ? scan1[tid - off] : 0;
        __syncthreads();
        scan1[tid] = v + add;
        __syncthreads();
    }
    const int base = (tid == 0) ? 0 : scan1[tid - 1];
    row_start[tid * 4 + 0] = base;
    row_start[tid * 4 + 1] = base + l0;
    row_start[tid * 4 + 2] = base + l0 + l1;
    row_start[tid * 4 + 3] = base + l0 + l1 + l2;
    sdeg[tid * 4 + 0] = base;
    sdeg[tid * 4 + 1] = base + l0;
    sdeg[tid * 4 + 2] = base + l0 + l1;
    sdeg[tid * 4 + 3] = base + l0 + l1 + l2;
    if (tid == 0) row_start[4096] = NE;
    __syncthreads();
    #pragma unroll
    for (int r = 0; r < NE / 1024; ++r) {
        const int e = r * 1024 + tid;
        const int d = eidx[NE + e];
        const int s = eidx[e];
        const int pos = atomicAdd(&sdeg[d], 1);
        srcs[pos] = s;
        epos[e] = pos;
    }
}

// ---------------------------------------------------------------------------
// Preamble mega-kernel:
//  [0,128)    weight convert/transpose fp32 [K][256] -> bf16 [256][K]
//  [128,192)  prop_add  (blk 128 also zeroes d_out)
//  [192,449)  Wfold = W3@W_out -> bf16 WfT[16][256] + bfv
//  [449,513)  eaP[slot][8] = eattr_e[0..4]  (CSR-slot order, 32B stride)
// ---------------------------------------------------------------------------
__global__ __launch_bounds__(256) void k_pre(
    const float* __restrict__ W_in, const float* __restrict__ W_msg,
    const float* __restrict__ W_upd, const float* __restrict__ W_add,
    const float* __restrict__ W1, const float* __restrict__ W2,
    const float* __restrict__ W3, const float* __restrict__ b3,
    const float* __restrict__ W_out, const float* __restrict__ b_out,
    const float* __restrict__ props, const float* __restrict__ W_prop,
    const float* __restrict__ b_prop, const float* __restrict__ b_add,
    const float* __restrict__ eattr, const int* __restrict__ epos,
    unsigned short* __restrict__ wbf, unsigned short* __restrict__ WfT,
    float* __restrict__ bfv, float* __restrict__ prop_add,
    float* __restrict__ eaP, float* __restrict__ dout)
{
    __shared__ __align__(16) char smem[16704];
    const int blk = blockIdx.x;
    const int tid = threadIdx.x;

    if (blk < 128) {                          // ---- weight convert/transpose
        float (*s)[65] = (float(*)[65])smem;
        const int wsel = blk >> 4;
        const int sub = blk & 15;
        const float* src; unsigned short* dst; int K = 256;
        switch (wsel) {
            case 0: src = W_in;              dst = wbf;                         K = 192; break;
            case 1: src = W_msg;             dst = wbf + 49152;                 break;
            case 2: src = W_upd;             dst = wbf + 49152 + 65536;         break;
            case 3: src = W_upd + 256 * 256; dst = wbf + 49152 + 2 * 65536;     break;
            case 4: src = W_add;             dst = wbf + 49152 + 3 * 65536;     break;
            case 5: src = W1;                dst = wbf + 49152 + 4 * 65536;     break;
            case 6: src = W1 + 256 * 256;    dst = wbf + 49152 + 5 * 65536;     break;
            default: src = W2;               dst = wbf + 49152 + 6 * 65536;     break;
        }
        const int k0 = (sub >> 2) * 64;
        const int n0 = (sub & 3) * 64;
        if (k0 >= K) return;
        const int tn = tid & 63;
        const int tg = tid >> 6;
        #pragma unroll
        for (int i = 0; i < 16; ++i) {
            const int kk = tg * 16 + i;
            s[kk][tn] = src[(size_t)(k0 + kk) * 256 + n0 + tn];
        }
        __syncthreads();
        #pragma unroll
        for (int i = 0; i < 16; ++i) {
            const int nn = tg * 16 + i;
            dst[(size_t)(n0 + nn) * K + k0 + tn] = f2bf(s[tn][nn]);
        }
    } else if (blk < 192) {                   // ---- prop_add (+ d_out zero)
        const int b = blk - 128;
        if (b == 0 && tid == 0) *dout = 0.f;
        const float pv = props[b];
        float acc = b_add[tid];
        #pragma unroll 8
        for (int p = 0; p < PD; ++p) {
            const float e = fmaf(pv, W_prop[p], b_prop[p]);
            acc = fmaf(e, W_add[(256 + p) * 256 + tid], acc);
        }
        prop_add[b * 256 + tid] = acc;
    } else if (blk < 449) {                   // ---- Wfold + bfv
        float* part = (float*)smem;           // [4][NET]
        const int cb = blk - 192;             // 0..256
        float acc[NET] = {0.f, 0.f, 0.f, 0.f, 0.f};
        #pragma unroll
        for (int rep = 0; rep < 2; ++rep) {
            const int j = rep * 256 + tid;
            const float wv = (cb < 256) ? W3[(size_t)cb * 512 + j] : b3[j];
            #pragma unroll
            for (int t = 0; t < NET; ++t) acc[t] = fmaf(wv, W_out[j * NET + t], acc[t]);
        }
        #pragma unroll
        for (int t = 0; t < NET; ++t)
            for (int off = 32; off >= 1; off >>= 1) acc[t] += __shfl_down(acc[t], off);
        if ((tid & 63) == 0) {
            #pragma unroll
            for (int t = 0; t < NET; ++t) part[(tid >> 6) * NET + t] = acc[t];
        }
        __syncthreads();
        if (tid == 0) {
            float s[NET];
            #pragma unroll
            for (int t = 0; t < NET; ++t)
                s[t] = part[t] + part[NET + t] + part[2 * NET + t] + part[3 * NET + t];
            if (cb < 256) {
                #pragma unroll
                for (int t = 0; t < NET; ++t) WfT[t * 256 + cb] = f2bf(s[t]);
                #pragma unroll
                for (int t = NET; t < 16; ++t) WfT[t * 256 + cb] = 0;
            } else {
                #pragma unroll
                for (int t = 0; t < NET; ++t) bfv[t] = s[t] + b_out[t];
            }
        }
    } else {                                  // ---- pack eattr into CSR order
        const int e = (blk - 449) * 256 + tid;
        const int pos = epos[e];
        const float a0 = eattr[e * 5 + 0];
        const float a1 = eattr[e * 5 + 1];
        const float a2 = eattr[e * 5 + 2];
        const float a3 = eattr[e * 5 + 3];
        const float a4 = eattr[e * 5 + 4];
        float* dst = eaP + (size_t)pos * 8;
        float4 v; v.x = a0; v.y = a1; v.z = a2; v.w = a3;
        *(float4*)dst = v;
        dst[4] = a4;
    }
}

// ---------------------------------------------------------------------------
// Fused node step. 1024 threads = 16 waves; 16 node-rows/block (grid 256).
// This round: explicit load BATCHING for memory-level parallelism —
//   agg: 8 CSR slots per batch (8 srcs/eaP loads, then 8 P-row loads, then math)
//   GEMM phases: all 8 B-fragments of a K-pass loaded into regs before MFMAs.
// ---------------------------------------------------------------------------
__global__ __launch_bounds__(1024) void fstep(
    const float* __restrict__ x, const unsigned short* __restrict__ hbuf,
    const unsigned short* __restrict__ Pin,
    const int* __restrict__ row_start, const int* __restrict__ srcs,
    const float* __restrict__ eaP, const float* __restrict__ Wme,
    const float* __restrict__ bmsg,
    const unsigned short* __restrict__ WaT, const unsigned short* __restrict__ WbT,
    const float* __restrict__ bias1,
    const unsigned short* __restrict__ Wp2T, const float* __restrict__ prop_add,
    const unsigned short* __restrict__ W1aT, const unsigned short* __restrict__ W1bT,
    unsigned short* __restrict__ hout, unsigned short* __restrict__ out1,
    unsigned short* __restrict__ out2, int mode)
{
    __shared__ __align__(16) unsigned short Hg[16 * FSTR];   // staged h tile
    __shared__ __align__(16) unsigned short Ag[16 * FSTR];   // agg tile (bf16)
    __shared__ __align__(16) unsigned short Hs[16 * FSTR];   // act
    __shared__ __align__(16) unsigned short H2s[16 * FSTR];  // embg (mode 2)
    const int tid = threadIdx.x;
    const int w = tid >> 6;          // 0..15
    const int lane = tid & 63;
    const int q = lane >> 4;
    const int tx = lane & 15;
    const int m0 = blockIdx.x * 16;
    const int col = w * 16 + tx;

    // ---- phase A: stage h tile + wave-per-node agg with batched gather
    if (mode != 0) {
        {
            const int r = tid >> 6;
            const int c4 = (tid & 63) * 4;
            *(uint2*)&Hg[r * FSTR + c4] =
                *(const uint2*)(hbuf + (size_t)(m0 + r) * 256 + c4);
        }
        {
            const int c = lane * 4;
            const float4 w0 = *(const float4*)(Wme + 0 * 256 + c);
            const float4 w1 = *(const float4*)(Wme + 1 * 256 + c);
            const float4 w2 = *(const float4*)(Wme + 2 * 256 + c);
            const float4 w3 = *(const float4*)(Wme + 3 * 256 + c);
            const float4 w4 = *(const float4*)(Wme + 4 * 256 + c);
            const float4 bm = *(const float4*)(bmsg + c);
            const int node = m0 + w;
            const int beg = row_start[node];
            const int end = row_start[node + 1];
            float a0 = 0.f, a1 = 0.f, a2 = 0.f, a3 = 0.f;
            for (int base = beg; base < end; base += 8) {
                int sarr[8];
                float4 ea[8];
                float eaw[8];
                uint2 pv[8];
                #pragma unroll
                for (int i = 0; i < 8; ++i) {
                    const int idx = (base + i < end) ? (base + i) : beg;
                    sarr[i] = srcs[idx];
                    ea[i]  = *(const float4*)(eaP + (size_t)idx * 8);
                    eaw[i] = eaP[(size_t)idx * 8 + 4];
                }
                #pragma unroll
                for (int i = 0; i < 8; ++i)
                    pv[i] = *(const uint2*)(Pin + (size_t)sarr[i] * 256 + c);
                #pragma unroll
                for (int i = 0; i < 8; ++i) {
                    if (base + i < end) {
                        float t0 = bm.x, t1 = bm.y, t2 = bm.z, t3 = bm.w;
                        t0 = fmaf(ea[i].x, w0.x, t0); t1 = fmaf(ea[i].x, w0.y, t1);
                        t2 = fmaf(ea[i].x, w0.z, t2); t3 = fmaf(ea[i].x, w0.w, t3);
                        t0 = fmaf(ea[i].y, w1.x, t0); t1 = fmaf(ea[i].y, w1.y, t1);
                        t2 = fmaf(ea[i].y, w1.z, t2); t3 = fmaf(ea[i].y, w1.w, t3);
                        t0 = fmaf(ea[i].z, w2.x, t0); t1 = fmaf(ea[i].z, w2.y, t1);
                        t2 = fmaf(ea[i].z, w2.z, t2); t3 = fmaf(ea[i].z, w2.w, t3);
                        t0 = fmaf(ea[i].w, w3.x, t0); t1 = fmaf(ea[i].w, w3.y, t1);
                        t2 = fmaf(ea[i].w, w3.z, t2); t3 = fmaf(ea[i].w, w3.w, t3);
                        t0 = fmaf(eaw[i],  w4.x, t0); t1 = fmaf(eaw[i],  w4.y, t1);
                        t2 = fmaf(eaw[i],  w4.z, t2); t3 = fmaf(eaw[i],  w4.w, t3);
                        a0 += fmaxf(bf_lo(pv[i].x) + t0, 0.f);
                        a1 += fmaxf(bf_hi(pv[i].x) + t1, 0.f);
                        a2 += fmaxf(bf_lo(pv[i].y) + t2, 0.f);
                        a3 += fmaxf(bf_hi(pv[i].y) + t3, 0.f);
                    }
                }
            }
            uint2 o; o.x = pack2(a0, a1); o.y = pack2(a2, a3);
            *(uint2*)&Ag[w * FSTR + c] = o;
        }
        __syncthreads();
    }

    // ---- phase B: act = relu(A@W + b); B-fragments batched into registers
    f32x4 acc = (f32x4)0.f;
    if (mode == 0) {
        short8 Ba[6];
        #pragma unroll
        for (int s = 0; s < 6; ++s)
            Ba[s] = *(const short8*)(WaT + (size_t)col * 192 + s * 32 + q * 8);
        #pragma unroll
        for (int s = 0; s < 6; ++s) {
            const float* ap = x + (size_t)(m0 + tx) * 192 + s * 32 + q * 8;
            const float4 v0 = *(const float4*)ap;
            const float4 v1 = *(const float4*)(ap + 4);
            short8 af;
            af[0] = (short)f2bf(v0.x); af[1] = (short)f2bf(v0.y);
            af[2] = (short)f2bf(v0.z); af[3] = (short)f2bf(v0.w);
            af[4] = (short)f2bf(v1.x); af[5] = (short)f2bf(v1.y);
            af[6] = (short)f2bf(v1.z); af[7] = (short)f2bf(v1.w);
            acc = __builtin_amdgcn_mfma_f32_16x16x32_bf16(af, Ba[s], acc, 0, 0, 0);
        }
    } else {
        short8 Ba[8], Bb[8];
        #pragma unroll
        for (int s = 0; s < 8; ++s)
            Ba[s] = *(const short8*)(WaT + (size_t)col * 256 + s * 32 + q * 8);
        #pragma unroll
        for (int s = 0; s < 8; ++s)
            Bb[s] = *(const short8*)(WbT + (size_t)col * 256 + s * 32 + q * 8);
        #pragma unroll
        for (int s = 0; s < 8; ++s) {
            const short8 af = *(const short8*)&Hg[tx * FSTR + s * 32 + q * 8];
            acc = __builtin_amdgcn_mfma_f32_16x16x32_bf16(af, Ba[s], acc, 0, 0, 0);
        }
        #pragma unroll
        for (int s = 0; s < 8; ++s) {
            const short8 af = *(const short8*)&Ag[tx * FSTR + s * 32 + q * 8];
            acc = __builtin_amdgcn_mfma_f32_16x16x32_bf16(af, Bb[s], acc, 0, 0, 0);
        }
    }
    {
        const float bv = bias1[col];
        #pragma unroll
        for (int r = 0; r < 4; ++r) {
            const int row = q * 4 + r;
            const unsigned short us = f2bf(fmaxf(acc[r] + bv, 0.f));
            Hs[row * FSTR + col] = us;
            if (mode < 2) hout[(size_t)(m0 + row) * 256 + col] = us;
        }
    }
    __syncthreads();

    // ---- phase C: act @ Wp2 (batched B)
    acc = (f32x4)0.f;
    {
        short8 Bc[8];
        #pragma unroll
        for (int s = 0; s < 8; ++s)
            Bc[s] = *(const short8*)(Wp2T + (size_t)col * 256 + s * 32 + q * 8);
        #pragma unroll
        for (int s = 0; s < 8; ++s) {
            const short8 af = *(const short8*)&Hs[tx * FSTR + s * 32 + q * 8];
            acc = __builtin_amdgcn_mfma_f32_16x16x32_bf16(af, Bc[s], acc, 0, 0, 0);
        }
    }
    if (mode < 2) {
        #pragma unroll
        for (int r = 0; r < 4; ++r)
            out1[(size_t)(m0 + q * 4 + r) * 256 + col] = f2bf(acc[r]);
        return;
    }
    {
        const float pv = prop_add[(m0 >> 6) * 256 + col];
        #pragma unroll
        for (int r = 0; r < 4; ++r)
            H2s[(q * 4 + r) * FSTR + col] = f2bf(acc[r] + pv);
    }
    __syncthreads();

    // ---- phase 2b: A1 = embg@W1a, A2 = embg@W1b (batched B)
    for (int which = 0; which < 2; ++which) {
        const unsigned short* WT = which ? W1bT : W1aT;
        unsigned short* op = which ? out2 : out1;
        acc = (f32x4)0.f;
        short8 Bd[8];
        #pragma unroll
        for (int s = 0; s < 8; ++s)
            Bd[s] = *(const short8*)(WT + (size_t)col * 256 + s * 32 + q * 8);
        #pragma unroll
        for (int s = 0; s < 8; ++s) {
            const short8 af = *(const short8*)&H2s[tx * FSTR + s * 32 + q * 8];
            acc = __builtin_amdgcn_mfma_f32_16x16x32_bf16(af, Bd[s], acc, 0, 0, 0);
        }
        #pragma unroll
        for (int r = 0; r < 4; ++r)
            op[(size_t)(m0 + q * 4 + r) * 256 + col] = f2bf(acc[r]);
    }
}

// ---------------------------------------------------------------------------
// Fused pair MLP + CE (validated). Grid 256 x 512; 4 tiles of 64 pairs per
// block; W2 fragments preloaded once into 32 short8 registers.
// ---------------------------------------------------------------------------
__global__ __launch_bounds__(512, 1) void pair_k(
    const unsigned short* __restrict__ A1t, const unsigned short* __restrict__ A2t,
    const float* __restrict__ b1, const unsigned short* __restrict__ W2T,
    const float* __restrict__ b2, const unsigned short* __restrict__ WfT,
    const float* __restrict__ bfv,
    const int* __restrict__ sel_b, const int* __restrict__ sel_i,
    const int* __restrict__ sel_j, const int* __restrict__ golden,
    float* __restrict__ out)
{
    __shared__ __align__(16) unsigned short sbuf[64 * H1STR];
    __shared__ __align__(16) unsigned short b1s[256];
    __shared__ float Lg[64 * 8];
    __shared__ int sidx[64 * PTILES], didx[64 * PTILES], gold[64 * PTILES];

    const int tid = threadIdx.x;
    const int w = tid >> 6;
    const int lane = tid & 63;
    const int q = lane >> 4;
    const int tx = lane & 15;
    const int m = lane & 31;
    const int hh = lane >> 5;
    const int e0 = blockIdx.x * 64 * PTILES;

    if (tid < 64 * PTILES) {
        const int e = e0 + tid;
        const int b = sel_b[e];
        sidx[tid] = b * N_PER_B + sel_i[e];
        didx[tid] = b * N_PER_B + sel_j[e];
        gold[tid] = golden[e];
    }
    if (tid < 256) b1s[tid] = f2bf(b1[tid]);

    const int pt = w & 1;
    const int cg = w >> 1;
    short8 Breg[32];
    {
        const unsigned short* bb = W2T + (size_t)(cg * 64 + m) * 256 + hh * 8;
        #pragma unroll
        for (int cc = 0; cc < 2; ++cc)
            #pragma unroll
            for (int s = 0; s < 16; ++s)
                Breg[cc * 16 + s] = *(const short8*)(bb + (size_t)cc * 32 * 256 + s * 16);
    }
    __syncthreads();

    float total = 0.f;

    for (int t = 0; t < PTILES; ++t) {
        {
            const int hw = tid >> 5;
            #pragma unroll
            for (int j = 0; j < 4; ++j) {
                const int p = j * 16 + hw;
                const unsigned short* r1 = A1t + (size_t)sidx[t * 64 + p] * 256 + m * 8;
                const unsigned short* r2 = A2t + (size_t)didx[t * 64 + p] * 256 + m * 8;
                const uint4 u1 = *(const uint4*)r1;
                const uint4 u2 = *(const uint4*)r2;
                const uint4 ub = *(const uint4*)(b1s + m * 8);
                uint2 lo2, hi2;
                lo2.x = addrelu2(u1.x, u2.x, ub.x);
                lo2.y = addrelu2(u1.y, u2.y, ub.y);
                hi2.x = addrelu2(u1.z, u2.z, ub.z);
                hi2.y = addrelu2(u1.w, u2.w, ub.w);
                unsigned short* dbase = sbuf + p * H1STR + m * 8;
                *(uint2*)(dbase) = lo2;
                *(uint2*)(dbase + 4) = hi2;
            }
        }
        __syncthreads();

        f32x16 acc0 = (f32x16)0.f;
        f32x16 acc1 = (f32x16)0.f;
        {
            const unsigned short* arow = sbuf + (size_t)(pt * 32 + m) * H1STR + hh * 8;
            #pragma unroll
            for (int s = 0; s < 16; ++s) {
                const short8 af = ld_frag(arow + s * 16);
                acc0 = __builtin_amdgcn_mfma_f32_32x32x16_bf16(af, Breg[s], acc0, 0, 0, 0);
                acc1 = __builtin_amdgcn_mfma_f32_32x32x16_bf16(af, Breg[16 + s], acc1, 0, 0, 0);
            }
        }
        __syncthreads();

        #pragma unroll
        for (int cc = 0; cc < 2; ++cc) {
            const f32x16* ap = cc ? &acc1 : &acc0;
            const int col = cg * 64 + cc * 32 + m;
            const float bv = b2[col];
            #pragma unroll
            for (int reg = 0; reg < 16; ++reg) {
                const int prow = pt * 32 + (reg & 3) + 8 * (reg >> 2) + 4 * hh;
                sbuf[prow * H1STR + col] = f2bf(fmaxf((*ap)[reg] + bv, 0.f));
            }
        }
        __syncthreads();

        if (w < 4) {
            f32x4 accL = (f32x4)0.f;
            const unsigned short* a2row = sbuf + (size_t)(w * 16 + tx) * H1STR + q * 8;
            const unsigned short* bWf = WfT + (size_t)tx * 256 + q * 8;
            #pragma unroll
            for (int s = 0; s < 8; ++s) {
                const short8 af = ld_frag(a2row + s * 32);
                const short8 bfr = *(const short8*)(bWf + s * 32);
                accL = __builtin_amdgcn_mfma_f32_16x16x32_bf16(af, bfr, accL, 0, 0, 0);
            }
            if (tx < NET) {
                const float bb = bfv[tx];
                #pragma unroll
                for (int reg = 0; reg < 4; ++reg)
                    Lg[(w * 16 + q * 4 + reg) * 8 + tx] = accL[reg] + bb;
            }
        }
        __syncthreads();

        if (tid < 64) {
            float lg[NET];
            #pragma unroll
            for (int tt = 0; tt < NET; ++tt) lg[tt] = Lg[tid * 8 + tt];
            float mx = lg[0];
            #pragma unroll
            for (int tt = 1; tt < NET; ++tt) mx = fmaxf(mx, lg[tt]);
            float s = 0.f;
            #pragma unroll
            for (int tt = 0; tt < NET; ++tt) s += expf(lg[tt] - mx);
            float ls = mx + logf(s) - lg[gold[t * 64 + tid]];
            #pragma unroll
            for (int off = 32; off >= 1; off >>= 1) ls += __shfl_xor(ls, off);
            total += ls;
        }
        __syncthreads();
    }

    if (tid == 0) atomicAdd(out, total * (1.0f / NSEL));
}

// ---------------------------------------------------------------------------
extern "C" void kernel_launch(void* const* d_in, const int* in_sizes, int n_in,
                              void* d_out, int out_size, void* d_ws, size_t ws_size,
                              hipStream_t stream) {
    (void)in_sizes; (void)n_in; (void)out_size; (void)ws_size;
    const float* x      = (const float*)d_in[0];
    const int*   eidx   = (const int*)d_in[1];
    const float* eattr  = (const float*)d_in[2];
    const float* props  = (const float*)d_in[3];
    const int*   sel_b  = (const int*)d_in[4];
    const int*   sel_i  = (const int*)d_in[5];
    const int*   sel_j  = (const int*)d_in[6];
    const int*   golden = (const int*)d_in[7];
    const float* W_prop = (const float*)d_in[8];
    const float* b_prop = (const float*)d_in[9];
    const float* W_in   = (const float*)d_in[10];
    const float* b_in   = (const float*)d_in[11];
    const float* W_msg  = (const float*)d_in[12];
    const float* b_msg  = (const float*)d_in[13];
    const float* W_upd  = (const float*)d_in[14];
    const float* b_upd  = (const float*)d_in[15];
    const float* W_add  = (const float*)d_in[16];
    const float* b_add  = (const float*)d_in[17];
    const float* W1     = (const float*)d_in[18];
    const float* b1     = (const float*)d_in[19];
    const float* W2     = (const float*)d_in[20];
    const float* b2     = (const float*)d_in[21];
    const float* W3     = (const float*)d_in[22];
    const float* b3     = (const float*)d_in[23];
    const float* W_out  = (const float*)d_in[24];
    const float* b_out  = (const float*)d_in[25];

    const size_t SEG = (size_t)BN * 256;
    unsigned short* P0   = (unsigned short*)d_ws;   // P even; final A1
    unsigned short* P1   = P0 + SEG;
    unsigned short* hA   = P1 + SEG;                // h double-buffer; final A2
    unsigned short* hB   = hA + SEG;
    unsigned short* wbf  = hB + SEG;
    unsigned short* W_inT  = wbf;                   // [256][192]
    unsigned short* WmT    = wbf + 49152;
    unsigned short* WuaT   = WmT + 65536;
    unsigned short* WubT   = WuaT + 65536;
    unsigned short* W_addT = WubT + 65536;
    unsigned short* W1aT   = W_addT + 65536;
    unsigned short* W1bT   = W1aT + 65536;
    unsigned short* W2T    = W1bT + 65536;
    unsigned short* WfT    = W2T + 65536;           // [16][256]
    float* prop_add = (float*)(WfT + 4096);         // [64][256]
    float* bfv  = prop_add + 64 * 256;              // [16]
    float* eaP  = bfv + 16;                         // [NE][8] CSR-slot order
    int* row_start = (int*)(eaP + (size_t)NE * 8);  // [4097]
    int* srcs      = row_start + 4104;              // [NE]
    int* epos      = srcs + NE;                     // [NE]

    csr_all<<<1, 1024, 0, stream>>>(eidx, row_start, srcs, epos);
    k_pre<<<513, 256, 0, stream>>>(W_in, W_msg, W_upd, W_add, W1, W2, W3, b3,
                                   W_out, b_out, props, W_prop, b_prop, b_add,
                                   eattr, epos, wbf, WfT, bfv, prop_add,
                                   eaP, (float*)d_out);

    const float* Wme = W_msg + 256 * 256;
    // round 0: h0 = relu(x@W_in+b) -> hA; P0 = h0@Wm
    fstep<<<256, 1024, 0, stream>>>(x, nullptr, nullptr, row_start, srcs, eaP, Wme, b_msg,
                                    W_inT, nullptr, b_in, WmT, nullptr, nullptr, nullptr,
                                    hA, P0, nullptr, 0);
    // rounds 1..3: agg(P) -> h' -> P'
    fstep<<<256, 1024, 0, stream>>>(nullptr, hA, P0, row_start, srcs, eaP, Wme, b_msg,
                                    WuaT, WubT, b_upd, WmT, nullptr, nullptr, nullptr,
                                    hB, P1, nullptr, 1);
    fstep<<<256, 1024, 0, stream>>>(nullptr, hB, P1, row_start, srcs, eaP, Wme, b_msg,
                                    WuaT, WubT, b_upd, WmT, nullptr, nullptr, nullptr,
                                    hA, P0, nullptr, 1);
    fstep<<<256, 1024, 0, stream>>>(nullptr, hA, P0, row_start, srcs, eaP, Wme, b_msg,
                                    WuaT, WubT, b_upd, WmT, nullptr, nullptr, nullptr,
                                    hB, P1, nullptr, 1);
    // final: agg(P1) -> h4 -> embg -> A1 (P0), A2 (hA)
    fstep<<<256, 1024, 0, stream>>>(nullptr, hB, P1, row_start, srcs, eaP, Wme, b_msg,
                                    WuaT, WubT, b_upd, W_addT, prop_add, W1aT, W1bT,
                                    nullptr, P0, hA, 2);

    pair_k<<<256, 512, 0, stream>>>(P0, hA, b1, W2T, b2, WfT, bfv,
                                    sel_b, sel_i, sel_j, golden, (float*)d_out);
}